// Round 10
// baseline (119.854 us; speedup 1.0000x reference)
//
#include <hip/hip_runtime.h>
#include <hip/hip_fp16.h>
#include <math.h>

#define HN 8
#define HH 512
#define HW 512
#define NPIX (HH*HW)        // 262144 per image
#define NTOT (HN*NPIX)      // 2097152 total
#define INF1D 1.0e6f
#define BIGF 3.0e38f

// async global->LDS, 16B per lane (dest must be wave-uniform base + lane*16)
__device__ __forceinline__ void g2l16(const float* g, float* l) {
  __builtin_amdgcn_global_load_lds(
      (const __attribute__((address_space(1))) void*)g,
      (__attribute__((address_space(3))) void*)l, 16, 0, 0);
}

// ---------------------------------------------------------------------------
// Kernel A: per-row 1D distance (along W) for both feature sets, emitted as
// SIGNED SQUARED f32: v = +din^2 if pixel in m (dout==0), else -dout^2.
// Also zeroes the k_loss completion counter (block 0).
// One wave per row; each lane owns 8 consecutive pixels.
// ---------------------------------------------------------------------------
__global__ __launch_bounds__(256) void k_rows(const float* __restrict__ gt,
                                              float* __restrict__ sqg,
                                              unsigned int* __restrict__ ctr) {
  if (blockIdx.x == 0 && threadIdx.x == 0) ctr[0] = 0u;
  const int lane = threadIdx.x & 63;
  const int wv   = threadIdx.x >> 6;
  const int row  = blockIdx.x * 4 + wv;          // 0..4095 = n*512 + h
  const float* g = gt + (size_t)row * HW;

  float4 a0 = *(const float4*)(g + lane * 8);
  float4 a1 = *(const float4*)(g + lane * 8 + 4);
  float mv[8] = {a0.x, a0.y, a0.z, a0.w, a1.x, a1.y, a1.z, a1.w};

  float pin[8], pout[8], sfin[8], sfout[8];
  float rin = BIGF, rout = BIGF;
  for (int j = 0; j < 8; ++j) {
    float wf = (float)(lane * 8 + j);
    bool m = mv[j] > 0.5f;
    float gin  = m ? INF1D : 0.f;   // feature_in  = ~m
    float gout = m ? 0.f : INF1D;   // feature_out =  m
    rin  = fminf(rin,  gin  - wf);  pin[j]  = rin;
    rout = fminf(rout, gout - wf);  pout[j] = rout;
  }
  // exclusive wave prefix-min of lane totals
  float xin = rin, xout = rout;
  for (int off = 1; off < 64; off <<= 1) {
    float yi = __shfl_up(xin, off);
    float yo = __shfl_up(xout, off);
    if (lane >= off) { xin = fminf(xin, yi); xout = fminf(xout, yo); }
  }
  float ein  = __shfl_up(xin, 1);  if (lane == 0) ein  = BIGF;
  float eout = __shfl_up(xout, 1); if (lane == 0) eout = BIGF;

  float rsin = BIGF, rsout = BIGF;
  for (int j = 7; j >= 0; --j) {
    float wf = (float)(lane * 8 + j);
    bool m = mv[j] > 0.5f;
    float gin  = m ? INF1D : 0.f;
    float gout = m ? 0.f : INF1D;
    rsin  = fminf(rsin,  gin  + wf);  sfin[j]  = rsin;
    rsout = fminf(rsout, gout + wf);  sfout[j] = rsout;
  }
  float zin = rsin, zout = rsout;
  for (int off = 1; off < 64; off <<= 1) {
    float yi = __shfl_down(zin, off);
    float yo = __shfl_down(zout, off);
    if (lane + off < 64) { zin = fminf(zin, yi); zout = fminf(zout, yo); }
  }
  float sein  = __shfl_down(zin, 1);  if (lane == 63) sein  = BIGF;
  float seout = __shfl_down(zout, 1); if (lane == 63) seout = BIGF;

  float outp[8];
  for (int j = 0; j < 8; ++j) {
    float wf = (float)(lane * 8 + j);
    float fin  = wf + fminf(pin[j],  ein);
    float fout = wf + fminf(pout[j], eout);
    float bin  = fminf(sfin[j],  sein)  - wf;
    float bout = fminf(sfout[j], seout) - wf;
    float g1i = fminf(fin,  bin);    // dist_in  (0 if pixel outside m)
    float g1o = fminf(fout, bout);   // dist_out (0 if pixel inside  m)
    outp[j] = (g1o == 0.f) ? g1i * g1i : -(g1o * g1o);
  }
  float* dst = sqg + (size_t)row * HW + lane * 8;
  *(float4*)dst       = make_float4(outp[0], outp[1], outp[2], outp[3]);
  *(float4*)(dst + 4) = make_float4(outp[4], outp[5], outp[6], outp[7]);
}

// ---------------------------------------------------------------------------
// Kernel B: column pass. Block = 64 cols x 64 output rows; window +-32 halo
// (<=128 rows). LDS = signed-squared f32 plane, stride 64 (wave compute read
// = one full 64-word row -> 2 lanes/bank, conflict-free). Staging is a pure
// global_load_lds DMA. 17-register rolling window per thread (compile-time
// indices only). Probe: fmax(sgn*v,0)+dk^2 == fmax(fma(sgn,v,dk^2), dk^2).
// Clamped-index probes exact. dk=1..8 unconditional; guarded LDS tail dk>=9.
// sd stored as f16 (|sd|<=~724, rel err 5e-4 -> bd err ~1e-4 << 3e-2 thr).
// ---------------------------------------------------------------------------
#define ICH 64
#define HALO 32
__global__ __launch_bounds__(256) void k_cols(const float* __restrict__ sqg,
                                              __half* __restrict__ sdh,
                                              float* __restrict__ partials) {
  __shared__ float sq[128 * 64];          // 32 KB
  const int tid = threadIdx.x;
  const int wx = blockIdx.x;              // 0..7  w-tile
  const int iy = blockIdx.y;              // 0..7  i-chunk
  const int n  = blockIdx.z;
  const int I0 = iy * ICH;
  const int kb = max(0, I0 - HALO);
  const int ke = min(HH, I0 + ICH + HALO);
  const int sz = ke - kb;                 // 96 or 128
  const int w0 = wx * 64;
  const float* src = sqg + (size_t)n * NPIX + (size_t)kb * HW + w0;

  const int total4 = sz * 16;             // multiple of 256
  for (int p4 = tid; p4 < total4; p4 += 256) {
    int row = p4 >> 4;
    int c4  = (p4 & 15) << 2;
    g2l16(src + (size_t)row * HW + c4, &sq[p4 << 2]);
  }
  __syncthreads();

  const int lane = tid & 63;
  const int wv   = tid >> 6;
  const int col  = lane;
  const int base = (I0 - kb) + wv * 16;
  float lmax = -BIGF;

  float w[17];
#pragma unroll
  for (int t = 0; t < 17; ++t) {
    int rw = min(max(base - 8 + t, 0), sz - 1);
    w[t] = sq[rw * 64 + col];
  }

#pragma unroll
  for (int q = 0; q < 16; ++q) {
    const float own = w[(8 + q) % 17];
    const bool  m   = own > 0.f;
    const float sgn = m ? 1.f : -1.f;
    float best = fabsf(own);
#pragma unroll
    for (int dk = 1; dk <= 8; ++dk) {
      const float dkk = (float)(dk * dk);
      float a = fmaxf(__builtin_fmaf(sgn, w[(8 + q - dk + 17) % 17], dkk), dkk);
      float b = fmaxf(__builtin_fmaf(sgn, w[(8 + q + dk) % 17],      dkk), dkk);
      best = fminf(best, a);
      best = fminf(best, b);
    }
    const int li = base + q;
    for (int dk = 9; dk < 128; ++dk) {    // rare exact tail
      float dkk = (float)(dk * dk);
      if (__all(dkk >= best)) break;
      float a = fmaxf(__builtin_fmaf(sgn, sq[max(li - dk, 0) * 64 + col], dkk), dkk);
      float b = fmaxf(__builtin_fmaf(sgn, sq[min(li + dk, sz - 1) * 64 + col], dkk), dkk);
      best = fminf(best, a);
      best = fminf(best, b);
    }
    const int i = I0 + wv * 16 + q;
    float s = m ? sqrtf(best) : -sqrtf(best);
    sdh[(size_t)n * NPIX + (size_t)i * HW + w0 + col] = __float2half(s);
    lmax = fmaxf(lmax, s);
    if (q < 15) {
      int rw = min(base + q + 9, sz - 1);
      w[q % 17] = sq[rw * 64 + col];
    }
  }
  for (int off = 32; off; off >>= 1) lmax = fmaxf(lmax, __shfl_xor(lmax, off));
  if (lane == 0) partials[((n * 8 + iy) * 8 + wx) * 4 + wv] = lmax;
}

// ---------------------------------------------------------------------------
// Kernel C: fused loss + FINAL REDUCE (last-block-done). Each block: inline
// wsmax reduce (256 floats, L2), elementwise terms (8 px/thread, fully
// unrolled, sd as f16), block partials to private slot, __threadfence +
// atomicAdd(ctr); the 1024th block re-reduces partials2 and emits the scalar.
// ---------------------------------------------------------------------------
__global__ __launch_bounds__(256) void k_loss(const float* __restrict__ seg_p,
                                              const float* __restrict__ seg_t,
                                              const float* __restrict__ edge_p,
                                              const float* __restrict__ edge_t,
                                              const __half* __restrict__ sdh,
                                              const float* __restrict__ partials,
                                              float* __restrict__ partials2,
                                              unsigned int* __restrict__ ctr,
                                              float* __restrict__ out) {
  const int n = blockIdx.x >> 7;
  const int tid = threadIdx.x;
  const int wv = tid >> 6, ln = tid & 63;

  // inline wsmax reduce (256 values, one per thread)
  float v = partials[n * 256 + tid];
  for (int off = 32; off; off >>= 1) v = fmaxf(v, __shfl_xor(v, off));
  __shared__ float smax[4];
  if (ln == 0) smax[wv] = v;
  __syncthreads();
  const float mx = fmaxf(fmaxf(smax[0], smax[1]), fmaxf(smax[2], smax[3]));
  const float inv = (mx > 0.f) ? 1.f / (mx + 1e-6f) : 1.f;
  const float HI = 1.0f - 1e-7f;

  const size_t base = (size_t)n * NPIX + (size_t)(blockIdx.x & 127) * 2048
                    + (size_t)tid * 8;

  float4 pA = *(const float4*)(seg_p  + base);
  float4 pB = *(const float4*)(seg_p  + base + 4);
  float4 tA = *(const float4*)(seg_t  + base);
  float4 tB = *(const float4*)(seg_t  + base + 4);
  float4 eA = *(const float4*)(edge_p + base);
  float4 eB = *(const float4*)(edge_p + base + 4);
  float4 gA = *(const float4*)(edge_t + base);
  float4 gB = *(const float4*)(edge_t + base + 4);
  uint4  sv = *(const uint4*)(sdh + base);     // 8 halves

  float pa[8]  = {pA.x, pA.y, pA.z, pA.w, pB.x, pB.y, pB.z, pB.w};
  float ta[8]  = {tA.x, tA.y, tA.z, tA.w, tB.x, tB.y, tB.z, tB.w};
  float epa[8] = {eA.x, eA.y, eA.z, eA.w, eB.x, eB.y, eB.z, eB.w};
  float eta[8] = {gA.x, gA.y, gA.z, gA.w, gB.x, gB.y, gB.z, gB.w};
  float sa[8];
  {
    float2 f;
    f = __half22float2(*(const __half2*)&sv.x); sa[0] = f.x; sa[1] = f.y;
    f = __half22float2(*(const __half2*)&sv.y); sa[2] = f.x; sa[3] = f.y;
    f = __half22float2(*(const __half2*)&sv.z); sa[4] = f.x; sa[5] = f.y;
    f = __half22float2(*(const __half2*)&sv.w); sa[6] = f.x; sa[7] = f.y;
  }

  float a_bce = 0.f, a_pt = 0.f, a_ps = 0.f, a_ts = 0.f, a_ed = 0.f, a_bd = 0.f;
#pragma unroll
  for (int j = 0; j < 8; ++j) {
    float p = pa[j], t = ta[j];
    float pc = fminf(fmaxf(p, 1e-7f), HI);
    bool tm = t > 0.5f;
    a_bce -= __logf(tm ? pc : 1.f - pc);
    a_pt  += p * t;
    a_ps  += p;
    a_ts  += t;
    float ep = epa[j], et = eta[j];
    float ec = fminf(fmaxf(ep, 1e-7f), HI);
    bool em = et > 0.5f;
    a_ed -= __logf(em ? ec : 1.f - ec) * (em ? 0.9f : 0.1f);
    float sn = sa[j] * inv;
    sn = fminf(fmaxf(sn, -1.f), 1.f);
    a_bd += fabsf(p - t) * fabsf(sn);
  }
  for (int off = 32; off; off >>= 1) {
    a_bce += __shfl_xor(a_bce, off);
    a_pt  += __shfl_xor(a_pt,  off);
    a_ps  += __shfl_xor(a_ps,  off);
    a_ts  += __shfl_xor(a_ts,  off);
    a_ed  += __shfl_xor(a_ed,  off);
    a_bd  += __shfl_xor(a_bd,  off);
  }
  __shared__ float red[4][6];
  if (ln == 0) {
    red[wv][0] = a_bce; red[wv][1] = a_pt; red[wv][2] = a_ps;
    red[wv][3] = a_ts;  red[wv][4] = a_ed; red[wv][5] = a_bd;
  }
  __syncthreads();
  __shared__ bool lastf;
  if (tid == 0) {
    float* dst = partials2 + (size_t)blockIdx.x * 8;
    dst[0] = red[0][0] + red[1][0] + red[2][0] + red[3][0];
    dst[1] = red[0][1] + red[1][1] + red[2][1] + red[3][1];
    dst[2] = red[0][2] + red[1][2] + red[2][2] + red[3][2];
    dst[3] = red[0][3] + red[1][3] + red[2][3] + red[3][3];
    dst[4] = red[0][4] + red[1][4] + red[2][4] + red[3][4];
    dst[5] = red[0][5] + red[1][5] + red[2][5] + red[3][5];
    __threadfence();
    lastf = (atomicAdd(ctr, 1u) == (HN * 128 - 1));
  }
  __syncthreads();
  if (!lastf) return;

  // ---- last block: final reduce of 1024 block-partials + scalar ----
  __threadfence();
  const int nn = tid >> 5;     // image 0..7
  const int l  = tid & 31;
  float s0 = 0.f, s1 = 0.f, s2 = 0.f, s3 = 0.f, s4 = 0.f, s5 = 0.f;
#pragma unroll
  for (int it = 0; it < 4; ++it) {
    const float* p = partials2 + (size_t)((nn * 128) + l + it * 32) * 8;
    s0 += p[0]; s1 += p[1]; s2 += p[2];
    s3 += p[3]; s4 += p[4]; s5 += p[5];
  }
  for (int off = 16; off; off >>= 1) {
    s0 += __shfl_xor(s0, off); s1 += __shfl_xor(s1, off);
    s2 += __shfl_xor(s2, off); s3 += __shfl_xor(s3, off);
    s4 += __shfl_xor(s4, off); s5 += __shfl_xor(s5, off);
  }
  __shared__ float red2[8][6];
  if (l == 0) {
    red2[nn][0] = s0; red2[nn][1] = s1; red2[nn][2] = s2;
    red2[nn][3] = s3; red2[nn][4] = s4; red2[nn][5] = s5;
  }
  __syncthreads();
  if (tid == 0) {
    const float M = (float)NTOT;
    float bce = 0.f, ed = 0.f, bd = 0.f, dsum = 0.f;
    for (int k = 0; k < HN; ++k) {
      bce += red2[k][0]; ed += red2[k][4]; bd += red2[k][5];
      float den = red2[k][2] + red2[k][3] + 1e-6f;
      dsum += 2.f * red2[k][1] / den;
    }
    float dice = 1.f - dsum / (float)HN;
    out[0] = bce / M + 0.5f * dice + 0.5f * (ed / M) + 0.2f * (bd / M);
  }
}

extern "C" void kernel_launch(void* const* d_in, const int* in_sizes, int n_in,
                              void* d_out, int out_size, void* d_ws, size_t ws_size,
                              hipStream_t stream) {
  const float* seg_p  = (const float*)d_in[0];
  const float* seg_t  = (const float*)d_in[1];
  const float* edge_p = (const float*)d_in[2];
  const float* edge_t = (const float*)d_in[3];
  float* out = (float*)d_out;

  char* ws = (char*)d_ws;
  float*  sqg       = (float*)ws;                              // 8 MB: signed d^2 row dists
  __half* sdh       = (__half*)(ws + (size_t)NTOT * 4);        // 4 MB: signed distance f16
  float*  partials  = (float*)(ws + (size_t)NTOT * 8);         // 8*256 floats (k_cols wave maxes)
  float*  partials2 = partials + 8 * 256;                      // 1024*8 floats (k_loss partials)
  unsigned int* ctr = (unsigned int*)(partials2 + 1024 * 8);   // completion counter

  k_rows<<<dim3(HN * HH / 4), 256, 0, stream>>>(seg_t, sqg, ctr);
  k_cols<<<dim3(8, 8, HN), 256, 0, stream>>>(sqg, sdh, partials);
  k_loss<<<dim3(HN * 128), 256, 0, stream>>>(seg_p, seg_t, edge_p, edge_t, sdh,
                                             partials, partials2, ctr, out);
}

// Round 11
// 94.510 us; speedup vs baseline: 1.2682x; 1.2682x over previous
//
#include <hip/hip_runtime.h>
#include <hip/hip_fp16.h>
#include <math.h>

#define HN 8
#define HH 512
#define HW 512
#define NPIX (HH*HW)        // 262144 per image
#define NTOT (HN*NPIX)      // 2097152 total
#define INF1D 1.0e6f
#define BIGF 3.0e38f

// async global->LDS, 16B per lane (dest must be wave-uniform base + lane*16)
__device__ __forceinline__ void g2l16(const float* g, float* l) {
  __builtin_amdgcn_global_load_lds(
      (const __attribute__((address_space(1))) void*)g,
      (__attribute__((address_space(3))) void*)l, 16, 0, 0);
}

// ---------------------------------------------------------------------------
// Kernel A: per-row 1D distance (along W) for both feature sets, emitted as
// SIGNED SQUARED f32: v = +din^2 if pixel in m (dout==0), else -dout^2.
// One wave per row; each lane owns 8 consecutive pixels.
// ---------------------------------------------------------------------------
__global__ __launch_bounds__(256) void k_rows(const float* __restrict__ gt,
                                              float* __restrict__ sqg) {
  const int lane = threadIdx.x & 63;
  const int wv   = threadIdx.x >> 6;
  const int row  = blockIdx.x * 4 + wv;          // 0..4095 = n*512 + h
  const float* g = gt + (size_t)row * HW;

  float4 a0 = *(const float4*)(g + lane * 8);
  float4 a1 = *(const float4*)(g + lane * 8 + 4);
  float mv[8] = {a0.x, a0.y, a0.z, a0.w, a1.x, a1.y, a1.z, a1.w};

  float pin[8], pout[8], sfin[8], sfout[8];
  float rin = BIGF, rout = BIGF;
  for (int j = 0; j < 8; ++j) {
    float wf = (float)(lane * 8 + j);
    bool m = mv[j] > 0.5f;
    float gin  = m ? INF1D : 0.f;   // feature_in  = ~m
    float gout = m ? 0.f : INF1D;   // feature_out =  m
    rin  = fminf(rin,  gin  - wf);  pin[j]  = rin;
    rout = fminf(rout, gout - wf);  pout[j] = rout;
  }
  // exclusive wave prefix-min of lane totals
  float xin = rin, xout = rout;
  for (int off = 1; off < 64; off <<= 1) {
    float yi = __shfl_up(xin, off);
    float yo = __shfl_up(xout, off);
    if (lane >= off) { xin = fminf(xin, yi); xout = fminf(xout, yo); }
  }
  float ein  = __shfl_up(xin, 1);  if (lane == 0) ein  = BIGF;
  float eout = __shfl_up(xout, 1); if (lane == 0) eout = BIGF;

  float rsin = BIGF, rsout = BIGF;
  for (int j = 7; j >= 0; --j) {
    float wf = (float)(lane * 8 + j);
    bool m = mv[j] > 0.5f;
    float gin  = m ? INF1D : 0.f;
    float gout = m ? 0.f : INF1D;
    rsin  = fminf(rsin,  gin  + wf);  sfin[j]  = rsin;
    rsout = fminf(rsout, gout + wf);  sfout[j] = rsout;
  }
  float zin = rsin, zout = rsout;
  for (int off = 1; off < 64; off <<= 1) {
    float yi = __shfl_down(zin, off);
    float yo = __shfl_down(zout, off);
    if (lane + off < 64) { zin = fminf(zin, yi); zout = fminf(zout, yo); }
  }
  float sein  = __shfl_down(zin, 1);  if (lane == 63) sein  = BIGF;
  float seout = __shfl_down(zout, 1); if (lane == 63) seout = BIGF;

  float outp[8];
  for (int j = 0; j < 8; ++j) {
    float wf = (float)(lane * 8 + j);
    float fin  = wf + fminf(pin[j],  ein);
    float fout = wf + fminf(pout[j], eout);
    float bin  = fminf(sfin[j],  sein)  - wf;
    float bout = fminf(sfout[j], seout) - wf;
    float g1i = fminf(fin,  bin);    // dist_in  (0 if pixel outside m)
    float g1o = fminf(fout, bout);   // dist_out (0 if pixel inside  m)
    outp[j] = (g1o == 0.f) ? g1i * g1i : -(g1o * g1o);
  }
  float* dst = sqg + (size_t)row * HW + lane * 8;
  *(float4*)dst       = make_float4(outp[0], outp[1], outp[2], outp[3]);
  *(float4*)(dst + 4) = make_float4(outp[4], outp[5], outp[6], outp[7]);
}

// ---------------------------------------------------------------------------
// Kernel B: column pass. Block = 64 cols x 64 output rows; window +-32 halo
// (<=128 rows). LDS = signed-squared f32 plane, stride 64 (wave compute read
// = one full 64-word row -> 2 lanes/bank, conflict-free). Staging is a pure
// global_load_lds DMA. 17-register rolling window per thread (compile-time
// indices only). Probe: fmax(sgn*v,0)+dk^2 == fmax(fma(sgn,v,dk^2), dk^2).
// Clamped-index probes exact. dk=1..8 unconditional; guarded LDS tail dk>=9.
// sd stored as f16 (|sd|<=~724, rel err 5e-4 -> bd err ~1e-4 << 3e-2 thr).
// ---------------------------------------------------------------------------
#define ICH 64
#define HALO 32
__global__ __launch_bounds__(256) void k_cols(const float* __restrict__ sqg,
                                              __half* __restrict__ sdh,
                                              float* __restrict__ partials) {
  __shared__ float sq[128 * 64];          // 32 KB
  const int tid = threadIdx.x;
  const int wx = blockIdx.x;              // 0..7  w-tile
  const int iy = blockIdx.y;              // 0..7  i-chunk
  const int n  = blockIdx.z;
  const int I0 = iy * ICH;
  const int kb = max(0, I0 - HALO);
  const int ke = min(HH, I0 + ICH + HALO);
  const int sz = ke - kb;                 // 96 or 128
  const int w0 = wx * 64;
  const float* src = sqg + (size_t)n * NPIX + (size_t)kb * HW + w0;

  const int total4 = sz * 16;             // multiple of 256
  for (int p4 = tid; p4 < total4; p4 += 256) {
    int row = p4 >> 4;
    int c4  = (p4 & 15) << 2;
    g2l16(src + (size_t)row * HW + c4, &sq[p4 << 2]);
  }
  __syncthreads();

  const int lane = tid & 63;
  const int wv   = tid >> 6;
  const int col  = lane;
  const int base = (I0 - kb) + wv * 16;
  float lmax = -BIGF;

  float w[17];
#pragma unroll
  for (int t = 0; t < 17; ++t) {
    int rw = min(max(base - 8 + t, 0), sz - 1);
    w[t] = sq[rw * 64 + col];
  }

#pragma unroll
  for (int q = 0; q < 16; ++q) {
    const float own = w[(8 + q) % 17];
    const bool  m   = own > 0.f;
    const float sgn = m ? 1.f : -1.f;
    float best = fabsf(own);
#pragma unroll
    for (int dk = 1; dk <= 8; ++dk) {
      const float dkk = (float)(dk * dk);
      float a = fmaxf(__builtin_fmaf(sgn, w[(8 + q - dk + 17) % 17], dkk), dkk);
      float b = fmaxf(__builtin_fmaf(sgn, w[(8 + q + dk) % 17],      dkk), dkk);
      best = fminf(best, a);
      best = fminf(best, b);
    }
    const int li = base + q;
    for (int dk = 9; dk < 128; ++dk) {    // rare exact tail
      float dkk = (float)(dk * dk);
      if (__all(dkk >= best)) break;
      float a = fmaxf(__builtin_fmaf(sgn, sq[max(li - dk, 0) * 64 + col], dkk), dkk);
      float b = fmaxf(__builtin_fmaf(sgn, sq[min(li + dk, sz - 1) * 64 + col], dkk), dkk);
      best = fminf(best, a);
      best = fminf(best, b);
    }
    const int i = I0 + wv * 16 + q;
    float s = m ? sqrtf(best) : -sqrtf(best);
    sdh[(size_t)n * NPIX + (size_t)i * HW + w0 + col] = __float2half(s);
    lmax = fmaxf(lmax, s);
    if (q < 15) {
      int rw = min(base + q + 9, sz - 1);
      w[q % 17] = sq[rw * 64 + col];
    }
  }
  for (int off = 32; off; off >>= 1) lmax = fmaxf(lmax, __shfl_xor(lmax, off));
  if (lane == 0) partials[((n * 8 + iy) * 8 + wx) * 4 + wv] = lmax;
}

// ---------------------------------------------------------------------------
// Kernel C: fused loss. Inline wsmax reduce (256 floats, L2), elementwise
// terms (8 px/thread, fully unrolled, 9 independent vector loads, sd as f16),
// block partials to PRIVATE 32-B slots. No atomics, no fences (R10 lesson:
// per-block device-scope fence+atomic costs ~45 ns x 1024 blocks = 47 us).
// ---------------------------------------------------------------------------
__global__ __launch_bounds__(256) void k_loss(const float* __restrict__ seg_p,
                                              const float* __restrict__ seg_t,
                                              const float* __restrict__ edge_p,
                                              const float* __restrict__ edge_t,
                                              const __half* __restrict__ sdh,
                                              const float* __restrict__ partials,
                                              float* __restrict__ partials2) {
  const int n = blockIdx.x >> 7;
  const int tid = threadIdx.x;
  const int wv = tid >> 6, ln = tid & 63;

  // inline wsmax reduce (256 values, one per thread)
  float v = partials[n * 256 + tid];
  for (int off = 32; off; off >>= 1) v = fmaxf(v, __shfl_xor(v, off));
  __shared__ float smax[4];
  if (ln == 0) smax[wv] = v;
  __syncthreads();
  const float mx = fmaxf(fmaxf(smax[0], smax[1]), fmaxf(smax[2], smax[3]));
  const float inv = (mx > 0.f) ? 1.f / (mx + 1e-6f) : 1.f;
  const float HI = 1.0f - 1e-7f;

  const size_t base = (size_t)n * NPIX + (size_t)(blockIdx.x & 127) * 2048
                    + (size_t)tid * 8;

  float4 pA = *(const float4*)(seg_p  + base);
  float4 pB = *(const float4*)(seg_p  + base + 4);
  float4 tA = *(const float4*)(seg_t  + base);
  float4 tB = *(const float4*)(seg_t  + base + 4);
  float4 eA = *(const float4*)(edge_p + base);
  float4 eB = *(const float4*)(edge_p + base + 4);
  float4 gA = *(const float4*)(edge_t + base);
  float4 gB = *(const float4*)(edge_t + base + 4);
  uint4  sv = *(const uint4*)(sdh + base);     // 8 halves

  float pa[8]  = {pA.x, pA.y, pA.z, pA.w, pB.x, pB.y, pB.z, pB.w};
  float ta[8]  = {tA.x, tA.y, tA.z, tA.w, tB.x, tB.y, tB.z, tB.w};
  float epa[8] = {eA.x, eA.y, eA.z, eA.w, eB.x, eB.y, eB.z, eB.w};
  float eta[8] = {gA.x, gA.y, gA.z, gA.w, gB.x, gB.y, gB.z, gB.w};
  float sa[8];
  {
    float2 f;
    f = __half22float2(*(const __half2*)&sv.x); sa[0] = f.x; sa[1] = f.y;
    f = __half22float2(*(const __half2*)&sv.y); sa[2] = f.x; sa[3] = f.y;
    f = __half22float2(*(const __half2*)&sv.z); sa[4] = f.x; sa[5] = f.y;
    f = __half22float2(*(const __half2*)&sv.w); sa[6] = f.x; sa[7] = f.y;
  }

  float a_bce = 0.f, a_pt = 0.f, a_ps = 0.f, a_ts = 0.f, a_ed = 0.f, a_bd = 0.f;
#pragma unroll
  for (int j = 0; j < 8; ++j) {
    float p = pa[j], t = ta[j];
    float pc = fminf(fmaxf(p, 1e-7f), HI);
    bool tm = t > 0.5f;
    a_bce -= __logf(tm ? pc : 1.f - pc);
    a_pt  += p * t;
    a_ps  += p;
    a_ts  += t;
    float ep = epa[j], et = eta[j];
    float ec = fminf(fmaxf(ep, 1e-7f), HI);
    bool em = et > 0.5f;
    a_ed -= __logf(em ? ec : 1.f - ec) * (em ? 0.9f : 0.1f);
    float sn = sa[j] * inv;
    sn = fminf(fmaxf(sn, -1.f), 1.f);
    a_bd += fabsf(p - t) * fabsf(sn);
  }
  for (int off = 32; off; off >>= 1) {
    a_bce += __shfl_xor(a_bce, off);
    a_pt  += __shfl_xor(a_pt,  off);
    a_ps  += __shfl_xor(a_ps,  off);
    a_ts  += __shfl_xor(a_ts,  off);
    a_ed  += __shfl_xor(a_ed,  off);
    a_bd  += __shfl_xor(a_bd,  off);
  }
  __shared__ float red[4][6];
  if (ln == 0) {
    red[wv][0] = a_bce; red[wv][1] = a_pt; red[wv][2] = a_ps;
    red[wv][3] = a_ts;  red[wv][4] = a_ed; red[wv][5] = a_bd;
  }
  __syncthreads();
  if (tid == 0) {
    float* dst = partials2 + (size_t)blockIdx.x * 8;
    dst[0] = red[0][0] + red[1][0] + red[2][0] + red[3][0];
    dst[1] = red[0][1] + red[1][1] + red[2][1] + red[3][1];
    dst[2] = red[0][2] + red[1][2] + red[2][2] + red[3][2];
    dst[3] = red[0][3] + red[1][3] + red[2][3] + red[3][3];
    dst[4] = red[0][4] + red[1][4] + red[2][4] + red[3][4];
    dst[5] = red[0][5] + red[1][5] + red[2][5] + red[3][5];
  }
}

// ---------------------------------------------------------------------------
// Kernel D: final reduce of 1024 block-partials (32 KB, L2-resident) + scalar.
// ---------------------------------------------------------------------------
__global__ __launch_bounds__(256) void k_final(const float* __restrict__ partials2,
                                               float* __restrict__ out) {
  const int t = threadIdx.x;
  const int n = t >> 5;        // image 0..7
  const int l = t & 31;
  float s0 = 0.f, s1 = 0.f, s2 = 0.f, s3 = 0.f, s4 = 0.f, s5 = 0.f;
#pragma unroll
  for (int it = 0; it < 4; ++it) {
    const float* p = partials2 + (size_t)((n * 128) + l + it * 32) * 8;
    s0 += p[0]; s1 += p[1]; s2 += p[2];
    s3 += p[3]; s4 += p[4]; s5 += p[5];
  }
  for (int off = 16; off; off >>= 1) {
    s0 += __shfl_xor(s0, off); s1 += __shfl_xor(s1, off);
    s2 += __shfl_xor(s2, off); s3 += __shfl_xor(s3, off);
    s4 += __shfl_xor(s4, off); s5 += __shfl_xor(s5, off);
  }
  __shared__ float red[8][6];
  if (l == 0) {
    red[n][0] = s0; red[n][1] = s1; red[n][2] = s2;
    red[n][3] = s3; red[n][4] = s4; red[n][5] = s5;
  }
  __syncthreads();
  if (t == 0) {
    const float M = (float)NTOT;
    float bce = 0.f, ed = 0.f, bd = 0.f, dsum = 0.f;
    for (int nn = 0; nn < HN; ++nn) {
      bce += red[nn][0]; ed += red[nn][4]; bd += red[nn][5];
      float den = red[nn][2] + red[nn][3] + 1e-6f;
      dsum += 2.f * red[nn][1] / den;
    }
    float dice = 1.f - dsum / (float)HN;
    out[0] = bce / M + 0.5f * dice + 0.5f * (ed / M) + 0.2f * (bd / M);
  }
}

extern "C" void kernel_launch(void* const* d_in, const int* in_sizes, int n_in,
                              void* d_out, int out_size, void* d_ws, size_t ws_size,
                              hipStream_t stream) {
  const float* seg_p  = (const float*)d_in[0];
  const float* seg_t  = (const float*)d_in[1];
  const float* edge_p = (const float*)d_in[2];
  const float* edge_t = (const float*)d_in[3];
  float* out = (float*)d_out;

  char* ws = (char*)d_ws;
  float*  sqg       = (float*)ws;                              // 8 MB: signed d^2 row dists
  __half* sdh       = (__half*)(ws + (size_t)NTOT * 4);        // 4 MB: signed distance f16
  float*  partials  = (float*)(ws + (size_t)NTOT * 8);         // 8*256 floats (k_cols wave maxes)
  float*  partials2 = partials + 8 * 256;                      // 1024*8 floats (k_loss partials)

  k_rows<<<dim3(HN * HH / 4), 256, 0, stream>>>(seg_t, sqg);
  k_cols<<<dim3(8, 8, HN), 256, 0, stream>>>(sqg, sdh, partials);
  k_loss<<<dim3(HN * 128), 256, 0, stream>>>(seg_p, seg_t, edge_p, edge_t, sdh,
                                             partials, partials2);
  k_final<<<1, 256, 0, stream>>>(partials2, out);
}